// Round 12
// baseline (4393.067 us; speedup 1.0000x reference)
//
#include <hip/hip_runtime.h>
#include <hip/hip_fp16.h>
#include <stdint.h>

// SymmetricQuantLinear: out[m,n] = scale[n] * sum_k x[m,k] * (nib(k,n) - 8)
//   x: f32 [M][K] (fp16-origin), packed: int32 [K/2][N], scale f32 [N].
//   Out f32 [M][N].
// Round 12: R11 deep pipeline with 2 LDS slots (64 KB) -> 2 blocks/CU
//   (cross-block overlap hides barrier/latency bubbles, m114 mechanism).
//   256x256, BK=32, 8 waves, counted vmcnt(4) (never 0 in loop),
//   source-pre-swizzled global_load_lds staging (0 bank conflicts),
//   static x2 slot unroll, setprio around MFMA cluster.

#define M_DIM 4096
#define K_DIM 4096
#define N_DIM 11008
#define KH    (K_DIM / 2)

#define WS_XH_BYTES  ((size_t)M_DIM * K_DIM * 2)            // 32 MiB

typedef __attribute__((ext_vector_type(8))) _Float16 f16x8;
typedef __attribute__((ext_vector_type(2))) _Float16 h2;
typedef __attribute__((ext_vector_type(4))) float f32x4;

__device__ __forceinline__ unsigned pack_f16_pair(float lo, float hi) {
    return __builtin_bit_cast(unsigned, __builtin_amdgcn_cvt_pkrtz(lo, hi));
}

__device__ __forceinline__ unsigned dq_pair(unsigned v) {
    // byte v = (hi<<4)|lo  ->  packed fp16 (lo-8, hi-8), exact.
    unsigned c = (v & 0xFu) | ((v << 12) & 0x000F0000u) | 0x64006400u;
    h2 r = __builtin_bit_cast(h2, c) + __builtin_bit_cast(h2, 0xE408E408u);
    return __builtin_bit_cast(unsigned, r);
}

__device__ __forceinline__ void gld_lds16(const void* g, void* l) {
    __builtin_amdgcn_global_load_lds(
        (const __attribute__((address_space(1))) unsigned int*)g,
        (__attribute__((address_space(3))) unsigned int*)l,
        16, 0, 0);
}

// ---- Pass 1a: X f32 -> fp16 (exact) ----
__global__ void __launch_bounds__(256) cvt_x_kernel(
    const float* __restrict__ X, unsigned short* __restrict__ Xh)
{
    size_t i = ((size_t)blockIdx.x * 256 + threadIdx.x) * 8;
    float4 a = *(const float4*)(X + i);
    float4 b = *(const float4*)(X + i + 4);
    uint4 o = make_uint4(pack_f16_pair(a.x, a.y), pack_f16_pair(a.z, a.w),
                         pack_f16_pair(b.x, b.y), pack_f16_pair(b.z, b.w));
    *(uint4*)(Xh + i) = o;
}

// ---- Pass 1b: WP [KH][N] -> Wt uint32 [N][KH] (fp16 [N][K] transposed) ----
__global__ void __launch_bounds__(256) dqt_kernel(
    const int* __restrict__ WP, unsigned* __restrict__ Wt)
{
    __shared__ unsigned Lt[64][65];
    const int t = threadIdx.x;
    const int n0 = blockIdx.x * 64;
    const int r0 = blockIdx.y * 64;
    const int g = t >> 6, l = t & 63;
#pragma unroll
    for (int i = 0; i < 16; ++i) {
        const int r = r0 + g * 16 + i;
        Lt[l][g * 16 + i] = dq_pair((unsigned)WP[(size_t)r * N_DIM + n0 + l]);
    }
    __syncthreads();
    const int nr = t >> 2, sg = t & 3;
    unsigned* dst = Wt + (size_t)(n0 + nr) * KH + r0 + sg * 16;
#pragma unroll
    for (int c = 0; c < 4; ++c) {
        uint4 v = make_uint4(Lt[nr][sg * 16 + c * 4 + 0], Lt[nr][sg * 16 + c * 4 + 1],
                             Lt[nr][sg * 16 + c * 4 + 2], Lt[nr][sg * 16 + c * 4 + 3]);
        *(uint4*)(dst + c * 4) = v;
    }
}

// ---- Pass 2: deep-pipelined fp16 GEMM, 2 slots, 2 blocks/CU ----
__global__ void __launch_bounds__(512, 4) qgemm5_kernel(
    const unsigned short* __restrict__ Xh,   // fp16 [M][K]
    const unsigned*       __restrict__ Wt,   // uint32 [N][KH] (fp16 [N][K])
    const float*          __restrict__ WS,   // [N]
    float*                __restrict__ Out)  // f32 [M][N]
{
    __shared__ unsigned short As[2][256 * 32];   // 16 KB per slot
    __shared__ unsigned short Bs[2][256 * 32];   // 64 KB total

    const int t = threadIdx.x;     // 0..511
    const int w = t >> 6;          // wave 0..7
    const int l = t & 63;

    // XCD swizzle: 688 blocks = 8 * 86 (bijective).
    const int bid = blockIdx.x;
    const int wg  = (bid & 7) * 86 + (bid >> 3);
    const int by  = wg / 43;                 // 0..15
    const int bx  = wg - by * 43;            // 0..42
    const int bm0 = by * 256;
    const int bn0 = bx * 256;

    const int wr = w >> 2;         // 0..1  -> 128 rows
    const int wc = w & 3;          // 0..3  -> 64 cols

    f32x4 acc[8][4];
#pragma unroll
    for (int i = 0; i < 8; ++i)
#pragma unroll
        for (int j = 0; j < 4; ++j)
            acc[i][j] = (f32x4){0.f, 0.f, 0.f, 0.f};

    // ---- staging (source-pre-swizzled, LDS dest linear; R10-validated) ----
    const int r0 = t >> 2;
    const int c0 = t & 3;
    const int cS = c0 ^ ((r0 >> 1) & 3);
    const unsigned short* gA0 = Xh + (size_t)(bm0 + r0) * K_DIM + cS * 8;
    const unsigned short* gA1 = Xh + (size_t)(bm0 + r0 + 128) * K_DIM + cS * 8;
    const unsigned*       gB0 = Wt + (size_t)(bn0 + r0) * KH + cS * 4;
    const unsigned*       gB1 = Wt + (size_t)(bn0 + r0 + 128) * KH + cS * 4;
    const int ldst = t * 8;        // ushort idx; +4096 for j=1

#define STAGE(s, kt) do {                                                     \
    gld_lds16(gA0 + (size_t)(kt) * 32, &As[s][ldst]);                         \
    gld_lds16(gA1 + (size_t)(kt) * 32, &As[s][ldst + 4096]);                  \
    gld_lds16(gB0 + (size_t)(kt) * 16, &Bs[s][ldst]);                         \
    gld_lds16(gB1 + (size_t)(kt) * 16, &Bs[s][ldst + 4096]);                  \
} while (0)

    const int lq = l >> 4;
    const int lr = l & 15;

#define MFMA_STEP(s) do {                                                     \
    f16x8 _af[8], _bf[4];                                                     \
    _Pragma("unroll")                                                         \
    for (int mi = 0; mi < 8; ++mi) {                                          \
        const int _r = wr * 128 + mi * 16 + lr;                               \
        _af[mi] = *(const f16x8*)&As[s][_r * 32 + (lq ^ ((_r >> 1) & 3)) * 8]; \
    }                                                                         \
    _Pragma("unroll")                                                         \
    for (int ni = 0; ni < 4; ++ni) {                                          \
        const int _r = wc * 64 + ni * 16 + lr;                                \
        _bf[ni] = *(const f16x8*)&Bs[s][_r * 32 + (lq ^ ((_r >> 1) & 3)) * 8]; \
    }                                                                         \
    __builtin_amdgcn_s_setprio(1);                                            \
    _Pragma("unroll")                                                         \
    for (int mi = 0; mi < 8; ++mi)                                            \
        _Pragma("unroll")                                                     \
        for (int ni = 0; ni < 4; ++ni)                                        \
            acc[mi][ni] = __builtin_amdgcn_mfma_f32_16x16x32_f16(             \
                _af[mi], _bf[ni], acc[mi][ni], 0, 0, 0);                      \
    __builtin_amdgcn_s_setprio(0);                                            \
} while (0)

#define WAITV(n) asm volatile("s_waitcnt vmcnt(" #n ")" ::: "memory")
#define BAR()    do { asm volatile("" ::: "memory");                          \
                      __builtin_amdgcn_s_barrier();                           \
                      asm volatile("" ::: "memory"); } while (0)

    const int NT = K_DIM / 32;   // 128

    // prologue: slots 0,1 <- tiles 0,1 (8 loads in flight)
    STAGE(0, 0);
    STAGE(1, 1);

    // main loop: static x2 slot rotation; vmcnt never drained to 0.
    for (int kt = 0; kt < NT - 2; kt += 2) {
        WAITV(4);                 // tile kt landed (tile kt+1's 4 in flight)
        BAR();
        MFMA_STEP(0);
        BAR();                    // slot0 reads done -> safe to overwrite
        STAGE(0, kt + 2);

        WAITV(4);                 // tile kt+1 landed
        BAR();
        MFMA_STEP(1);
        BAR();
        STAGE(1, kt + 3);
    }
    // tail: tiles 126 (slot0), 127 (slot1)
    WAITV(4);
    BAR();
    MFMA_STEP(0);
    WAITV(0);
    BAR();
    MFMA_STEP(1);

    // epilogue: per-column scale, f32 store
#pragma unroll
    for (int ni = 0; ni < 4; ++ni) {
        const int col = bn0 + wc * 64 + ni * 16 + lr;
        const float s = WS[col];
#pragma unroll
        for (int mi = 0; mi < 8; ++mi) {
            const int row = bm0 + wr * 128 + mi * 16 + lq * 4;
#pragma unroll
            for (int i = 0; i < 4; ++i) {
                Out[(size_t)(row + i) * N_DIM + col] = acc[mi][ni][i] * s;
            }
        }
    }
#undef STAGE
#undef MFMA_STEP
#undef WAITV
#undef BAR
}

extern "C" void kernel_launch(void* const* d_in, const int* in_sizes, int n_in,
                              void* d_out, int out_size, void* d_ws, size_t ws_size,
                              hipStream_t stream) {
    const float* X  = (const float*)d_in[0];
    const int*   WP = (const int*)d_in[1];
    const float* WS = (const float*)d_in[2];
    float*       Out = (float*)d_out;

    unsigned short* Xh = (unsigned short*)d_ws;
    unsigned*       Wt = (unsigned*)((char*)d_ws + WS_XH_BYTES);

    cvt_x_kernel<<<(M_DIM * K_DIM) / (256 * 8), 256, 0, stream>>>(X, Xh);
    dim3 gdq(N_DIM / 64, KH / 64);                    // 172 x 32
    dqt_kernel<<<gdq, 256, 0, stream>>>(WP, Wt);
    dim3 grid((N_DIM / 256) * (M_DIM / 256));         // 43 * 16 = 688
    qgemm5_kernel<<<grid, 512, 0, stream>>>(Xh, Wt, WS, Out);
}

// Round 13
// 475.445 us; speedup vs baseline: 9.2399x; 9.2399x over previous
//
#include <hip/hip_runtime.h>
#include <hip/hip_fp16.h>
#include <stdint.h>

// SymmetricQuantLinear: out[m,n] = scale[n] * sum_k x[m,k] * (nib(k,n) - 8)
//   x: f32 [M][K] (fp16-origin), packed: int32 [K/2][N], scale f32 [N].
//   Out f32 [M][N].
// Round 13: two-pass (validated prepasses) + 8-PHASE GEMM (m201-style):
//   256x256 tile, BK=64, 8 waves, 2 LDS dbufs (128 KB), per-phase
//   {stage half-tile || ds_read subtile || 16 MFMA}, barriers only at
//   K-tile boundaries, counted vmcnt(2) (never 0 in loop), setprio around
//   MFMA, R10-validated XOR swizzle adapted to 128B rows (byte ^= (row&7)<<4).
//   __launch_bounds__(512,2) — NOT 4 (R12: acc alone is 128 regs -> spill).

#define M_DIM 4096
#define K_DIM 4096
#define N_DIM 11008
#define KH    (K_DIM / 2)

#define WS_XH_BYTES  ((size_t)M_DIM * K_DIM * 2)            // 32 MiB

typedef __attribute__((ext_vector_type(8))) _Float16 f16x8;
typedef __attribute__((ext_vector_type(2))) _Float16 h2;
typedef __attribute__((ext_vector_type(4))) float f32x4;
typedef unsigned short ushortx;

__device__ __forceinline__ unsigned pack_f16_pair(float lo, float hi) {
    return __builtin_bit_cast(unsigned, __builtin_amdgcn_cvt_pkrtz(lo, hi));
}

__device__ __forceinline__ unsigned dq_pair(unsigned v) {
    // byte v = (hi<<4)|lo  ->  packed fp16 (lo-8, hi-8), exact.
    unsigned c = (v & 0xFu) | ((v << 12) & 0x000F0000u) | 0x64006400u;
    h2 r = __builtin_bit_cast(h2, c) + __builtin_bit_cast(h2, 0xE408E408u);
    return __builtin_bit_cast(unsigned, r);
}

__device__ __forceinline__ void gld_lds16(const void* g, void* l) {
    __builtin_amdgcn_global_load_lds(
        (const __attribute__((address_space(1))) unsigned int*)g,
        (__attribute__((address_space(3))) unsigned int*)l,
        16, 0, 0);
}

// ---- Pass 1a: X f32 -> fp16 (exact) ----
__global__ void __launch_bounds__(256) cvt_x_kernel(
    const float* __restrict__ X, unsigned short* __restrict__ Xh)
{
    size_t i = ((size_t)blockIdx.x * 256 + threadIdx.x) * 8;
    float4 a = *(const float4*)(X + i);
    float4 b = *(const float4*)(X + i + 4);
    uint4 o = make_uint4(pack_f16_pair(a.x, a.y), pack_f16_pair(a.z, a.w),
                         pack_f16_pair(b.x, b.y), pack_f16_pair(b.z, b.w));
    *(uint4*)(Xh + i) = o;
}

// ---- Pass 1b: WP [KH][N] -> Wt uint32 [N][KH] (fp16 [N][K] transposed) ----
__global__ void __launch_bounds__(256) dqt_kernel(
    const int* __restrict__ WP, unsigned* __restrict__ Wt)
{
    __shared__ unsigned Lt[64][65];
    const int t = threadIdx.x;
    const int n0 = blockIdx.x * 64;
    const int r0 = blockIdx.y * 64;
    const int g = t >> 6, l = t & 63;
#pragma unroll
    for (int i = 0; i < 16; ++i) {
        const int r = r0 + g * 16 + i;
        Lt[l][g * 16 + i] = dq_pair((unsigned)WP[(size_t)r * N_DIM + n0 + l]);
    }
    __syncthreads();
    const int nr = t >> 2, sg = t & 3;
    unsigned* dst = Wt + (size_t)(n0 + nr) * KH + r0 + sg * 16;
#pragma unroll
    for (int c = 0; c < 4; ++c) {
        uint4 v = make_uint4(Lt[nr][sg * 16 + c * 4 + 0], Lt[nr][sg * 16 + c * 4 + 1],
                             Lt[nr][sg * 16 + c * 4 + 2], Lt[nr][sg * 16 + c * 4 + 3]);
        *(uint4*)(dst + c * 4) = v;
    }
}

// ---- Pass 2: 8-phase fp16 GEMM ----
__global__ void __launch_bounds__(512, 2) qgemm6_kernel(
    const unsigned short* __restrict__ Xh,   // fp16 [M][K]
    const unsigned*       __restrict__ Wt,   // uint32 [N][KH] (fp16 [N][K])
    const float*          __restrict__ WS,   // [N]
    float*                __restrict__ Out)  // f32 [M][N]
{
    // [dbuf][half][128 rows x 64 ushort], swizzled slot = s ^ (row&7)
    __shared__ unsigned short LA[2][2][8192];
    __shared__ unsigned short LB[2][2][8192];   // 128 KB total

    const int t = threadIdx.x;     // 0..511
    const int w = t >> 6;          // wave 0..7
    const int l = t & 63;

    // XCD swizzle: 688 blocks = 8 * 86 (bijective).
    const int bid = blockIdx.x;
    const int wg  = (bid & 7) * 86 + (bid >> 3);
    const int by  = wg / 43;                 // 0..15
    const int bx  = wg - by * 43;            // 0..42
    const int bm0 = by * 256;
    const int bn0 = bx * 256;

    const int wr = w >> 2;         // 0..1 -> A half
    const int wc = w & 3;          // 0..3 -> B: half = wc>>1, sub = wc&1

    f32x4 acc[8][4];
#pragma unroll
    for (int i = 0; i < 8; ++i)
#pragma unroll
        for (int j = 0; j < 4; ++j)
            acc[i][j] = (f32x4){0.f, 0.f, 0.f, 0.f};

    // ---- staging addresses ----
    // row within half = j*64 + (t>>3); 16B slot c0 = t&7;
    // source slot cS = c0 ^ (row&7) = (t&7) ^ ((t>>3)&7) (64 == 0 mod 8).
    const int cS = (t & 7) ^ ((t >> 3) & 7);
    const unsigned short* gA0 = Xh + (size_t)(bm0 + (t >> 3)) * K_DIM + cS * 8;
    const unsigned*       gB0 = Wt + (size_t)(bn0 + (t >> 3)) * KH + cS * 4;
    const int t8 = t * 8;          // LDS ushort idx (linear dest)

#define STAGE_A(buf, h, kt) do {                                              \
    gld_lds16(gA0 + (size_t)((h) * 128) * K_DIM + (size_t)(kt) * 64,          \
              &LA[buf][h][t8]);                                               \
    gld_lds16(gA0 + (size_t)((h) * 128 + 64) * K_DIM + (size_t)(kt) * 64,     \
              &LA[buf][h][4096 + t8]);                                        \
} while (0)

#define STAGE_B(buf, h, kt) do {                                              \
    gld_lds16(gB0 + (size_t)((h) * 128) * KH + (size_t)(kt) * 32,             \
              &LB[buf][h][t8]);                                               \
    gld_lds16(gB0 + (size_t)((h) * 128 + 64) * KH + (size_t)(kt) * 32,        \
              &LB[buf][h][4096 + t8]);                                        \
} while (0)

    const int lq = l >> 4;         // 0..3
    const int lr = l & 15;

    f16x8 bf[4][2];                // persists across a tile's 4 phases

#define LOAD_BF(buf) do {                                                     \
    _Pragma("unroll")                                                         \
    for (int ni = 0; ni < 4; ++ni) {                                          \
        const int rrow = (wc & 1) * 64 + ni * 16 + lr;                        \
        _Pragma("unroll")                                                     \
        for (int ks = 0; ks < 2; ++ks)                                        \
            bf[ni][ks] = *(const f16x8*)                                      \
                &LB[buf][wc >> 1][rrow * 64 + ((ks * 4 + lq) ^ (rrow & 7)) * 8]; \
    }                                                                         \
} while (0)

#define MFMA_PH(buf, p) do {                                                  \
    f16x8 _af[2][2];                                                          \
    _Pragma("unroll")                                                         \
    for (int mi2 = 0; mi2 < 2; ++mi2) {                                       \
        const int rrow = (2 * (p) + mi2) * 16 + lr;                           \
        _Pragma("unroll")                                                     \
        for (int ks = 0; ks < 2; ++ks)                                        \
            _af[mi2][ks] = *(const f16x8*)                                    \
                &LA[buf][wr][rrow * 64 + ((ks * 4 + lq) ^ (rrow & 7)) * 8];   \
    }                                                                         \
    __builtin_amdgcn_s_setprio(1);                                            \
    _Pragma("unroll")                                                         \
    for (int mi2 = 0; mi2 < 2; ++mi2)                                         \
        _Pragma("unroll")                                                     \
        for (int ni = 0; ni < 4; ++ni)                                        \
            _Pragma("unroll")                                                 \
            for (int ks = 0; ks < 2; ++ks)                                    \
                acc[2 * (p) + mi2][ni] = __builtin_amdgcn_mfma_f32_16x16x32_f16( \
                    _af[mi2][ks], bf[ni][ks], acc[2 * (p) + mi2][ni], 0, 0, 0); \
    __builtin_amdgcn_s_setprio(0);                                            \
} while (0)

#define WAITV(n) asm volatile("s_waitcnt vmcnt(" #n ")" ::: "memory")
#define BAR()    do { asm volatile("" ::: "memory");                          \
                      __builtin_amdgcn_s_barrier();                           \
                      asm volatile("" ::: "memory"); } while (0)

    const int NT = K_DIM / 64;     // 64 K-tiles; 2 per iteration

    // prologue: tile 0 -> dbuf0 (8 loads in flight)
    STAGE_A(0, 0, 0); STAGE_A(0, 1, 0);
    STAGE_B(0, 0, 0); STAGE_B(0, 1, 0);

    for (int i = 0; i < 31; ++i) {
        const int t1 = 2 * i + 1, t2 = 2 * i + 2;
        // ph0 (boundary): compute tile 2i (dbuf0); stage t1.Ah0 -> dbuf1
        BAR(); STAGE_A(1, 0, t1); WAITV(2); BAR();
        LOAD_BF(0); MFMA_PH(0, 0);
        STAGE_A(1, 1, t1); MFMA_PH(0, 1);          // ph1
        STAGE_B(1, 0, t1); MFMA_PH(0, 2);          // ph2
        STAGE_B(1, 1, t1); MFMA_PH(0, 3);          // ph3
        // ph4 (boundary): compute tile 2i+1 (dbuf1); stage t2.Ah0 -> dbuf0
        BAR(); STAGE_A(0, 0, t2); WAITV(2); BAR();
        LOAD_BF(1); MFMA_PH(1, 0);
        STAGE_A(0, 1, t2); MFMA_PH(1, 1);          // ph5
        STAGE_B(0, 0, t2); MFMA_PH(1, 2);          // ph6
        STAGE_B(0, 1, t2); MFMA_PH(1, 3);          // ph7
    }
    // tail (i=31): tiles 62 (dbuf0), 63 (dbuf1); no staging past tile 63
    {
        BAR(); STAGE_A(1, 0, 63); WAITV(2); BAR();
        LOAD_BF(0); MFMA_PH(0, 0);
        STAGE_A(1, 1, 63); MFMA_PH(0, 1);
        STAGE_B(1, 0, 63); MFMA_PH(0, 2);
        STAGE_B(1, 1, 63); MFMA_PH(0, 3);
        BAR(); WAITV(0); BAR();
        LOAD_BF(1); MFMA_PH(1, 0);
        MFMA_PH(1, 1);
        MFMA_PH(1, 2);
        MFMA_PH(1, 3);
    }

    // epilogue: per-column scale, f32 store
#pragma unroll
    for (int ni = 0; ni < 4; ++ni) {
        const int col = bn0 + wc * 64 + ni * 16 + lr;
        const float s = WS[col];
#pragma unroll
        for (int mi = 0; mi < 8; ++mi) {
            const int row = bm0 + wr * 128 + mi * 16 + lq * 4;
#pragma unroll
            for (int i = 0; i < 4; ++i) {
                Out[(size_t)(row + i) * N_DIM + col] = acc[mi][ni][i] * s;
            }
        }
    }
#undef STAGE_A
#undef STAGE_B
#undef LOAD_BF
#undef MFMA_PH
#undef WAITV
#undef BAR
}

extern "C" void kernel_launch(void* const* d_in, const int* in_sizes, int n_in,
                              void* d_out, int out_size, void* d_ws, size_t ws_size,
                              hipStream_t stream) {
    const float* X  = (const float*)d_in[0];
    const int*   WP = (const int*)d_in[1];
    const float* WS = (const float*)d_in[2];
    float*       Out = (float*)d_out;

    unsigned short* Xh = (unsigned short*)d_ws;
    unsigned*       Wt = (unsigned*)((char*)d_ws + WS_XH_BYTES);

    cvt_x_kernel<<<(M_DIM * K_DIM) / (256 * 8), 256, 0, stream>>>(X, Xh);
    dim3 gdq(N_DIM / 64, KH / 64);                    // 172 x 32
    dqt_kernel<<<gdq, 256, 0, stream>>>(WP, Wt);
    dim3 grid((N_DIM / 256) * (M_DIM / 256));         // 43 * 16 = 688
    qgemm6_kernel<<<grid, 512, 0, stream>>>(Xh, Wt, WS, Out);
}

// Round 14
// 474.446 us; speedup vs baseline: 9.2594x; 1.0021x over previous
//
#include <hip/hip_runtime.h>
#include <hip/hip_fp16.h>
#include <stdint.h>

// SymmetricQuantLinear: out[m,n] = scale[n] * sum_k x[m,k] * (nib(k,n) - 8)
//   x: f32 [M][K] (fp16-origin), packed: int32 [K/2][N], scale f32 [N].
//   Out f32 [M][N].
// Round 14: 256x256, BK=64, 8 waves, 2 dbufs (128 KB), m201-faithful phases:
//   per tile: entry {WAITV(2); BAR; 16 ds_read burst}; 4 phases of
//   {stage 2 gld_lds; BAR; lgkmcnt(0)+sched_barrier; setprio; 16 MFMA; BAR},
//   mid-tile WAITV(4) + af-half1 burst. Staging order B,B,Ac0,Ac1 ->
//   need-distance >= 2 phases; vmcnt never 0 mid-loop.
//   XCD map: XCD x owns M-rows {2x,2x+1}, N-major -> B panels L2-shared x2.
//   VGPR budget: acc 128 AGPR + frags 96 + misc <= 128 VGPR (2 waves/SIMD).

#define M_DIM 4096
#define K_DIM 4096
#define N_DIM 11008
#define KH    (K_DIM / 2)

#define WS_XH_BYTES  ((size_t)M_DIM * K_DIM * 2)            // 32 MiB

typedef __attribute__((ext_vector_type(8))) _Float16 f16x8;
typedef __attribute__((ext_vector_type(2))) _Float16 h2;
typedef __attribute__((ext_vector_type(4))) float f32x4;

__device__ __forceinline__ unsigned pack_f16_pair(float lo, float hi) {
    return __builtin_bit_cast(unsigned, __builtin_amdgcn_cvt_pkrtz(lo, hi));
}

__device__ __forceinline__ unsigned dq_pair(unsigned v) {
    unsigned c = (v & 0xFu) | ((v << 12) & 0x000F0000u) | 0x64006400u;
    h2 r = __builtin_bit_cast(h2, c) + __builtin_bit_cast(h2, 0xE408E408u);
    return __builtin_bit_cast(unsigned, r);
}

__device__ __forceinline__ void gld_lds16(const void* g, void* l) {
    __builtin_amdgcn_global_load_lds(
        (const __attribute__((address_space(1))) unsigned int*)g,
        (__attribute__((address_space(3))) unsigned int*)l,
        16, 0, 0);
}

// ---- Pass 1a: X f32 -> fp16 (exact) ----
__global__ void __launch_bounds__(256) cvt_x_kernel(
    const float* __restrict__ X, unsigned short* __restrict__ Xh)
{
    size_t i = ((size_t)blockIdx.x * 256 + threadIdx.x) * 8;
    float4 a = *(const float4*)(X + i);
    float4 b = *(const float4*)(X + i + 4);
    uint4 o = make_uint4(pack_f16_pair(a.x, a.y), pack_f16_pair(a.z, a.w),
                         pack_f16_pair(b.x, b.y), pack_f16_pair(b.z, b.w));
    *(uint4*)(Xh + i) = o;
}

// ---- Pass 1b: WP [KH][N] -> Wt uint32 [N][KH] ----
__global__ void __launch_bounds__(256) dqt_kernel(
    const int* __restrict__ WP, unsigned* __restrict__ Wt)
{
    __shared__ unsigned Lt[64][65];
    const int t = threadIdx.x;
    const int n0 = blockIdx.x * 64;
    const int r0 = blockIdx.y * 64;
    const int g = t >> 6, l = t & 63;
#pragma unroll
    for (int i = 0; i < 16; ++i) {
        const int r = r0 + g * 16 + i;
        Lt[l][g * 16 + i] = dq_pair((unsigned)WP[(size_t)r * N_DIM + n0 + l]);
    }
    __syncthreads();
    const int nr = t >> 2, sg = t & 3;
    unsigned* dst = Wt + (size_t)(n0 + nr) * KH + r0 + sg * 16;
#pragma unroll
    for (int c = 0; c < 4; ++c) {
        uint4 v = make_uint4(Lt[nr][sg * 16 + c * 4 + 0], Lt[nr][sg * 16 + c * 4 + 1],
                             Lt[nr][sg * 16 + c * 4 + 2], Lt[nr][sg * 16 + c * 4 + 3]);
        *(uint4*)(dst + c * 4) = v;
    }
}

// ---- Pass 2: 8-phase m201-style fp16 GEMM ----
__global__ void __launch_bounds__(512, 2) qgemm7_kernel(
    const unsigned short* __restrict__ Xh,   // fp16 [M][K]
    const unsigned*       __restrict__ Wt,   // uint32 [N][KH] (fp16 [N][K])
    const float*          __restrict__ WS,   // [N]
    float*                __restrict__ Out)  // f32 [M][N]
{
    __shared__ unsigned short LA[2][2][8192];   // [dbuf][half][128 x 64]
    __shared__ unsigned short LB[2][2][8192];   // 128 KB total

    const int t = threadIdx.x;     // 0..511
    const int w = t >> 6;          // wave 0..7
    const int l = t & 63;

    // XCD map: xcd owns M-rows {2x,2x+1}, N-major within.
    const int bid = blockIdx.x;                 // 0..687
    const int xcd = bid & 7;
    const int i8  = bid >> 3;                   // 0..85
    const int bx  = i8 >> 1;                    // 0..42
    const int by  = (xcd << 1) | (i8 & 1);      // 0..15
    const int bm0 = by * 256;
    const int bn0 = bx * 256;

    const int wr = w >> 2;         // A half
    const int wc = w & 3;          // B: half = wc>>1, quarter = wc&1

    f32x4 acc[8][4];
#pragma unroll
    for (int i = 0; i < 8; ++i)
#pragma unroll
        for (int j = 0; j < 4; ++j)
            acc[i][j] = (f32x4){0.f, 0.f, 0.f, 0.f};

    // staging addresses (source-pre-swizzled; LDS dest linear)
    const int cS = (t & 7) ^ ((t >> 3) & 7);
    const unsigned short* gA0 = Xh + (size_t)(bm0 + (t >> 3)) * K_DIM + cS * 8;
    const unsigned*       gB0 = Wt + (size_t)(bn0 + (t >> 3)) * KH + cS * 4;
    const int t8 = t * 8;

#define SB_H(buf, h, kt) do {                                                 \
    gld_lds16(gB0 + (size_t)((h) * 128) * KH + (size_t)(kt) * 32,             \
              &LB[buf][h][t8]);                                               \
    gld_lds16(gB0 + (size_t)((h) * 128 + 64) * KH + (size_t)(kt) * 32,        \
              &LB[buf][h][4096 + t8]);                                        \
} while (0)

#define SA_C0(buf, kt) do {                                                   \
    gld_lds16(gA0 + (size_t)(kt) * 64,                  &LA[buf][0][t8]);     \
    gld_lds16(gA0 + (size_t)128 * K_DIM + (size_t)(kt) * 64, &LA[buf][1][t8]); \
} while (0)

#define SA_C1(buf, kt) do {                                                   \
    gld_lds16(gA0 + (size_t)64 * K_DIM + (size_t)(kt) * 64,                   \
              &LA[buf][0][4096 + t8]);                                        \
    gld_lds16(gA0 + (size_t)192 * K_DIM + (size_t)(kt) * 64,                  \
              &LA[buf][1][4096 + t8]);                                        \
} while (0)

    const int lq = l >> 4;
    const int lr = l & 15;

    f16x8 af0[4][2], af1[4][2], bf0[2][2], bf1[2][2];

#define READ_AF(D, MH, ARR) do {                                              \
    _Pragma("unroll")                                                         \
    for (int mi = 0; mi < 4; ++mi) {                                          \
        const int row = (MH) * 64 + mi * 16 + lr;                             \
        _Pragma("unroll")                                                     \
        for (int ks = 0; ks < 2; ++ks)                                        \
            ARR[mi][ks] = *(const f16x8*)                                     \
                &LA[D][wr][row * 64 + (((ks * 4 + lq) ^ (row & 7)) * 8)];     \
    }                                                                         \
} while (0)

#define READ_BF(D, NH, ARR) do {                                              \
    _Pragma("unroll")                                                         \
    for (int n = 0; n < 2; ++n) {                                             \
        const int row = (wc & 1) * 64 + ((NH) * 2 + n) * 16 + lr;             \
        _Pragma("unroll")                                                     \
        for (int ks = 0; ks < 2; ++ks)                                        \
            ARR[n][ks] = *(const f16x8*)                                      \
                &LB[D][wc >> 1][row * 64 + (((ks * 4 + lq) ^ (row & 7)) * 8)]; \
    }                                                                         \
} while (0)

#define MFMA_Q(MH, NH, AFA, BFA) do {                                         \
    __builtin_amdgcn_s_setprio(1);                                            \
    _Pragma("unroll")                                                         \
    for (int mi = 0; mi < 4; ++mi)                                            \
        _Pragma("unroll")                                                     \
        for (int n = 0; n < 2; ++n)                                           \
            _Pragma("unroll")                                                 \
            for (int ks = 0; ks < 2; ++ks)                                    \
                acc[(MH) * 4 + mi][(NH) * 2 + n] =                            \
                    __builtin_amdgcn_mfma_f32_16x16x32_f16(                   \
                        AFA[mi][ks], BFA[n][ks],                              \
                        acc[(MH) * 4 + mi][(NH) * 2 + n], 0, 0, 0);           \
    __builtin_amdgcn_s_setprio(0);                                            \
} while (0)

#define WAITV(n) asm volatile("s_waitcnt vmcnt(" #n ")" ::: "memory")
#define LGKM0()  do { asm volatile("s_waitcnt lgkmcnt(0)" ::: "memory");      \
                      __builtin_amdgcn_sched_barrier(0); } while (0)
#define BAR()    __builtin_amdgcn_s_barrier()

    // One K-tile: D = dbuf of this tile; KTN = next tile idx; STG: stage next?
#define TILE_FULL(D, KTN) do {                                                \
    WAITV(2); BAR();                      /* B + Ac0 of this tile landed */   \
    READ_AF(D, 0, af0); READ_BF(D, 0, bf0); READ_BF(D, 1, bf1);               \
    SB_H(D ^ 1, 0, KTN); BAR(); LGKM0();                                      \
    MFMA_Q(0, 0, af0, bf0); BAR();                                            \
    SB_H(D ^ 1, 1, KTN); BAR();                                               \
    MFMA_Q(0, 1, af0, bf1); BAR();                                            \
    WAITV(4); BAR();                      /* Ac1 of this tile landed */       \
    SA_C0(D ^ 1, KTN); READ_AF(D, 1, af1); BAR(); LGKM0();                    \
    MFMA_Q(1, 1, af1, bf1); BAR();                                            \
    SA_C1(D ^ 1, KTN); BAR();                                                 \
    MFMA_Q(1, 0, af1, bf0); BAR();                                            \
} while (0)

#define TILE_LAST(D) do {                                                     \
    WAITV(2); BAR();                                                          \
    READ_AF(D, 0, af0); READ_BF(D, 0, bf0); READ_BF(D, 1, bf1);               \
    BAR(); LGKM0();                                                           \
    MFMA_Q(0, 0, af0, bf0); BAR();                                            \
    MFMA_Q(0, 1, af0, bf1); BAR();                                            \
    WAITV(0); BAR();                                                          \
    READ_AF(D, 1, af1); BAR(); LGKM0();                                       \
    MFMA_Q(1, 1, af1, bf1); BAR();                                            \
    MFMA_Q(1, 0, af1, bf0);                                                   \
} while (0)

    // prologue: stage tile 0 (order B,B,Ac0,Ac1) -> 8 loads in flight
    SB_H(0, 0, 0); SB_H(0, 1, 0); SA_C0(0, 0); SA_C1(0, 0);

    for (int i = 0; i < 31; ++i) {
        TILE_FULL(0, 2 * i + 1);          // tile 2i   (dbuf0), stages 2i+1
        TILE_FULL(1, 2 * i + 2);          // tile 2i+1 (dbuf1), stages 2i+2
    }
    TILE_FULL(0, 63);                     // tile 62, stages 63
    TILE_LAST(1);                         // tile 63

    // epilogue: per-column scale, f32 store
#pragma unroll
    for (int ni = 0; ni < 4; ++ni) {
        const int col = bn0 + wc * 64 + ni * 16 + lr;
        const float s = WS[col];
#pragma unroll
        for (int mi = 0; mi < 8; ++mi) {
            const int row = bm0 + wr * 128 + mi * 16 + lq * 4;
#pragma unroll
            for (int i = 0; i < 4; ++i) {
                Out[(size_t)(row + i) * N_DIM + col] = acc[mi][ni][i] * s;
            }
        }
    }
#undef SB_H
#undef SA_C0
#undef SA_C1
#undef READ_AF
#undef READ_BF
#undef MFMA_Q
#undef WAITV
#undef LGKM0
#undef BAR
#undef TILE_FULL
#undef TILE_LAST
}

extern "C" void kernel_launch(void* const* d_in, const int* in_sizes, int n_in,
                              void* d_out, int out_size, void* d_ws, size_t ws_size,
                              hipStream_t stream) {
    const float* X  = (const float*)d_in[0];
    const int*   WP = (const int*)d_in[1];
    const float* WS = (const float*)d_in[2];
    float*       Out = (float*)d_out;

    unsigned short* Xh = (unsigned short*)d_ws;
    unsigned*       Wt = (unsigned*)((char*)d_ws + WS_XH_BYTES);

    cvt_x_kernel<<<(M_DIM * K_DIM) / (256 * 8), 256, 0, stream>>>(X, Xh);
    dim3 gdq(N_DIM / 64, KH / 64);                    // 172 x 32
    dqt_kernel<<<gdq, 256, 0, stream>>>(WP, Wt);
    dim3 grid((N_DIM / 256) * (M_DIM / 256));         // 688
    qgemm7_kernel<<<grid, 512, 0, stream>>>(Xh, Wt, WS, Out);
}